// Round 2
// baseline (406.886 us; speedup 1.0000x reference)
//
#include <hip/hip_runtime.h>
#include <hip/hip_bf16.h>

// ---------------- problem constants ----------------
#define T_SEQ 8192
#define DMODEL 1024
#define DINNER 2048          // DI
#define NSTATE 16            // DS
#define NCH 128              // scan chunks
#define CL 64                // chunk length (NCH*CL = T_SEQ)

typedef __attribute__((ext_vector_type(8))) short bf16x8;   // 8 bf16 = 4 VGPRs (MFMA A/B frag)
typedef __attribute__((ext_vector_type(4))) float f32x4;    // MFMA C/D frag

__device__ __forceinline__ float bf2f(ushort u) {
  union { unsigned u; float f; } c; c.u = ((unsigned)u) << 16; return c.f;
}
__device__ __forceinline__ ushort f2bf(float f) {
  union { float f; unsigned u; } c; c.f = f;
  unsigned r = c.u + 0x7FFFu + ((c.u >> 16) & 1u);   // RNE
  return (ushort)(r >> 16);
}

#define GLD16(dst, src) __builtin_amdgcn_global_load_lds( \
    (const __attribute__((address_space(1))) void*)(src), \
    (__attribute__((address_space(3))) void*)(dst), 16, 0, 0)
#define SCHED_FENCE() __builtin_amdgcn_sched_barrier(0)
#define BAR() do { SCHED_FENCE(); __builtin_amdgcn_s_barrier(); SCHED_FENCE(); } while (0)

// ---------------- prep kernels ----------------
__global__ __launch_bounds__(256) void cast_bf16(const float* __restrict__ in,
                                                 ushort* __restrict__ out, int n4) {
  int i = blockIdx.x * 256 + threadIdx.x;
  if (i < n4) {
    float4 v = ((const float4*)in)[i];
    ushort4 o;
    o.x = f2bf(v.x); o.y = f2bf(v.y); o.z = f2bf(v.z); o.w = f2bf(v.w);
    ((ushort4*)out)[i] = o;
  }
}

// in[R][C] f32 -> out[C][R] bf16   (grid: (C/32, R/32), block (32,8))
__global__ __launch_bounds__(256) void transpose_bf16(const float* __restrict__ in,
                                                      ushort* __restrict__ out, int R, int C) {
  __shared__ float tile[32][33];
  int bx = blockIdx.x * 32;   // C base
  int by = blockIdx.y * 32;   // R base
  int x = threadIdx.x, y = threadIdx.y;
#pragma unroll
  for (int j = 0; j < 32; j += 8)
    tile[y + j][x] = in[(size_t)(by + y + j) * C + bx + x];
  __syncthreads();
#pragma unroll
  for (int j = 0; j < 32; j += 8)
    out[(size_t)(bx + y + j) * R + by + x] = f2bf(tile[x][y + j]);
}

// W_x[2048][33] f32 -> wx48[48][2048] bf16 (transposed, zero-padded rows 33..47)
__global__ __launch_bounds__(256) void wx_transpose_pad(const float* __restrict__ Wx,
                                                        ushort* __restrict__ wxT) {
  int idx = blockIdx.x * 256 + threadIdx.x;   // 48*2048
  int j = idx >> 11;
  int k = idx & 2047;
  wxT[idx] = (j < 33) ? f2bf(Wx[k * 33 + j]) : (ushort)0;
}

// ---------------- 8-phase 256x256 GEMM (T2+T3+T4+T5) ----------------
// C[M][N] = A[M][K] * B^T, A/B bf16 row-major K-contig. BM=BN=256, BK=64,
// 8 waves (2M x 4N), per-wave 128x64 output (8x4 16x16 frags).
// LDS: A [2buf][2half][128x64] + B same, 128 KiB total (dynamic).
// Swizzle: o ^= ((o>>7)&7)<<4 within each 16 KiB half (16B-granule XOR,
// conflict-free ds_read_b128). Applied via pre-swizzled global SOURCE with
// linear global_load_lds dest (rule #21), same XOR on read side.
// Stage schedule per tile t: P1:A1(t+1), P2:B1(t+1), P3:A0(t+2), P4:B0(t+2);
// one counted vmcnt(4) at end of P4 (slots: A last read P2, B last read P3;
// all of tile t+1 forced landed by t's P4 vmcnt).
template<int BF16OUT>
__global__ __launch_bounds__(512, 2) void gemm256(const ushort* __restrict__ A,
                                                  const ushort* __restrict__ B,
                                                  void* __restrict__ Cout,
                                                  int N, int K, int nbn) {
  extern __shared__ __align__(16) char smem[];
  const int tid = threadIdx.x;
  const int lane = tid & 63;
  const int wid = tid >> 6;
  const int wm = wid >> 2;      // 0..1
  const int wn = wid & 3;       // 0..3

  // XCD-bijective swizzle (m204 formula)
  const int nwg = gridDim.x;
  const int q = nwg >> 3, r = nwg & 7;
  const int xcd = blockIdx.x & 7, bidx = blockIdx.x >> 3;
  const int wg = (xcd < r ? xcd * (q + 1) : r * (q + 1) + (xcd - r) * q) + bidx;
  const int mbase = (wg / nbn) * 256;
  const int nbase = (wg % nbn) * 256;

  const int NT = K >> 6;

  // per-thread staging source coords (pre-swizzled: LDS[o] = global[swz(o)])
  const int o1 = tid * 16, o2 = o1 + 8192;
  const int s1 = o1 ^ (((o1 >> 7) & 7) << 4);
  const int s2 = o2 ^ (((o2 >> 7) & 7) << 4);
  const int r1 = s1 >> 7, c1 = ((s1 >> 4) & 7) * 8;
  const int r2 = (s2 >> 7) & 127, c2 = ((s2 >> 4) & 7) * 8;

  const ushort* a0p = A + (size_t)(mbase + r1) * K + c1;
  const ushort* a0q = A + (size_t)(mbase + r2) * K + c2;
  const ushort* a1p = a0p + (size_t)128 * K;
  const ushort* a1q = a0q + (size_t)128 * K;
  const ushort* b0p = B + (size_t)(nbase + r1) * K + c1;
  const ushort* b0q = B + (size_t)(nbase + r2) * K + c2;
  const ushort* b1p = b0p + (size_t)128 * K;
  const ushort* b1q = b0q + (size_t)128 * K;

  char* const smemB = smem + 65536;
  const int dstw = wid * 1024;

#define STAGE_A(t, h) do { \
    char* _d = smem + ((t) & 1) * 32768 + (h) * 16384 + dstw; \
    GLD16(_d, ((h) ? a1p : a0p) + (t) * 64); \
    GLD16(_d + 8192, ((h) ? a1q : a0q) + (t) * 64); } while (0)
#define STAGE_B(t, h) do { \
    char* _d = smemB + ((t) & 1) * 32768 + (h) * 16384 + dstw; \
    GLD16(_d, ((h) ? b1p : b0p) + (t) * 64); \
    GLD16(_d + 8192, ((h) ? b1q : b0q) + (t) * 64); } while (0)

  const int frow = lane & 15;
  const int fk2 = (lane >> 4) * 16;   // byte offset within row

  auto ldA = [&](int b, int m, int ks) -> bf16x8 {
    int o = (((m * 16 + frow) << 7) | (ks * 64 + fk2));
    o ^= ((o >> 7) & 7) << 4;
    return *(const bf16x8*)(smem + b * 32768 + wm * 16384 + o);
  };
  auto ldB = [&](int b, int n, int ks) -> bf16x8 {
    int o = ((((wn & 1) * 64 + n * 16 + frow) << 7) | (ks * 64 + fk2));
    o ^= ((o >> 7) & 7) << 4;
    return *(const bf16x8*)(smemB + b * 32768 + (wn >> 1) * 16384 + o);
  };

  f32x4 acc[8][4];
#pragma unroll
  for (int m = 0; m < 8; ++m)
#pragma unroll
    for (int n = 0; n < 4; ++n) acc[m][n] = (f32x4){0.f, 0.f, 0.f, 0.f};

  // prologue: tile0 complete + A0/B0 of tile1 in flight
  STAGE_A(0, 0); STAGE_A(0, 1); STAGE_B(0, 0); STAGE_B(0, 1);
  if (NT > 1) { STAGE_A(1, 0); STAGE_B(1, 0); }
  asm volatile("s_waitcnt vmcnt(4)" ::: "memory");
  BAR();

  bf16x8 a0[4][2], a1[4][2], b0[2][2], b1[2][2];

  for (int t = 0; t < NT; ++t) {
    const int bb = t & 1;
    // ---- P1: quadrant (m0..3, n0..1); reads A(m0)+B(n0)
#pragma unroll
    for (int m = 0; m < 4; ++m) { a0[m][0] = ldA(bb, m, 0); a0[m][1] = ldA(bb, m, 1); }
#pragma unroll
    for (int n = 0; n < 2; ++n) { b0[n][0] = ldB(bb, n, 0); b0[n][1] = ldB(bb, n, 1); }
    if (t + 1 < NT) STAGE_A(t + 1, 1);
    BAR();
    __builtin_amdgcn_s_setprio(1);
#pragma unroll
    for (int m = 0; m < 4; ++m)
#pragma unroll
      for (int n = 0; n < 2; ++n)
#pragma unroll
        for (int ks = 0; ks < 2; ++ks)
          acc[m][n] = __builtin_amdgcn_mfma_f32_16x16x32_bf16(a0[m][ks], b0[n][ks], acc[m][n], 0, 0, 0);
    __builtin_amdgcn_s_setprio(0);
    BAR();
    // ---- P2: quadrant (m4..7, n0..1); reads A(m1)
#pragma unroll
    for (int m = 0; m < 4; ++m) { a1[m][0] = ldA(bb, 4 + m, 0); a1[m][1] = ldA(bb, 4 + m, 1); }
    if (t + 1 < NT) STAGE_B(t + 1, 1);
    BAR();
    __builtin_amdgcn_s_setprio(1);
#pragma unroll
    for (int m = 0; m < 4; ++m)
#pragma unroll
      for (int n = 0; n < 2; ++n)
#pragma unroll
        for (int ks = 0; ks < 2; ++ks)
          acc[4 + m][n] = __builtin_amdgcn_mfma_f32_16x16x32_bf16(a1[m][ks], b0[n][ks], acc[4 + m][n], 0, 0, 0);
    __builtin_amdgcn_s_setprio(0);
    BAR();
    // ---- P3: quadrant (m4..7, n2..3); reads B(n1)
#pragma unroll
    for (int n = 0; n < 2; ++n) { b1[n][0] = ldB(bb, 2 + n, 0); b1[n][1] = ldB(bb, 2 + n, 1); }
    if (t + 2 < NT) STAGE_A(t + 2, 0);
    BAR();
    __builtin_amdgcn_s_setprio(1);
#pragma unroll
    for (int m = 0; m < 4; ++m)
#pragma unroll
      for (int n = 0; n < 2; ++n)
#pragma unroll
        for (int ks = 0; ks < 2; ++ks)
          acc[4 + m][2 + n] = __builtin_amdgcn_mfma_f32_16x16x32_bf16(a1[m][ks], b1[n][ks], acc[4 + m][2 + n], 0, 0, 0);
    __builtin_amdgcn_s_setprio(0);
    BAR();
    // ---- P4: quadrant (m0..3, n2..3); no reads (a0 held from P1, b1 from P3)
    if (t + 2 < NT) STAGE_B(t + 2, 0);
    BAR();
    __builtin_amdgcn_s_setprio(1);
#pragma unroll
    for (int m = 0; m < 4; ++m)
#pragma unroll
      for (int n = 0; n < 2; ++n)
#pragma unroll
        for (int ks = 0; ks < 2; ++ks)
          acc[m][2 + n] = __builtin_amdgcn_mfma_f32_16x16x32_bf16(a0[m][ks], b1[n][ks], acc[m][2 + n], 0, 0, 0);
    __builtin_amdgcn_s_setprio(0);
    if (t + 2 < NT) asm volatile("s_waitcnt vmcnt(4)" ::: "memory");
    else            asm volatile("s_waitcnt vmcnt(0)" ::: "memory");
    BAR();
  }

  // epilogue: C/D layout col=lane&15, row=(lane>>4)*4+reg
  const int crow0 = mbase + wm * 128 + (lane >> 4) * 4;
  const int ccol0 = nbase + wn * 64 + (lane & 15);
#pragma unroll
  for (int m = 0; m < 8; ++m)
#pragma unroll
    for (int n = 0; n < 4; ++n)
#pragma unroll
      for (int j = 0; j < 4; ++j) {
        int rr = crow0 + m * 16 + j;
        int cc = ccol0 + n * 16;
        float v = acc[m][n][j];
        if (BF16OUT) ((ushort*)Cout)[(size_t)rr * N + cc] = f2bf(v);
        else         ((float*) Cout)[(size_t)rr * N + cc] = v;
      }
#undef STAGE_A
#undef STAGE_B
}

// ---------------- thin GEMM: xdbl = xs @ W_x (N=48 pad), 4-way split-K ----------------
// grid (64, 4): block = 128 rows x 48 cols x Kseg 512. partials[4][8192][48] f32.
__global__ __launch_bounds__(256) void gemm_thin(const ushort* __restrict__ A,
                                                 const ushort* __restrict__ Bw,
                                                 float* __restrict__ part) {
  __shared__ __align__(16) ushort sA[128 * 64];   // 16 KB
  __shared__ __align__(16) ushort sB[48 * 64];    // 6 KB
  const int tid = threadIdx.x, lane = tid & 63, wid = tid >> 6;
  const int mbase = blockIdx.x * 128;
  const int kbase = blockIdx.y * 512;
  const int frow = lane & 15, fke = (lane >> 4) * 8;

  f32x4 acc[2][3];
#pragma unroll
  for (int m = 0; m < 2; ++m)
#pragma unroll
    for (int n = 0; n < 3; ++n) acc[m][n] = (f32x4){0.f, 0.f, 0.f, 0.f};

  for (int k0 = 0; k0 < 512; k0 += 64) {
    // stage A tile [128][64] via global_load_lds (4 rounds of 4 KB)
#pragma unroll
    for (int j = 0; j < 4; ++j) {
      int o = tid * 16 + j * 4096;
      int row = o >> 7, ke = ((o >> 4) & 7) * 8;
      GLD16((char*)sA + wid * 1024 + j * 4096,
            A + (size_t)(mbase + row) * DINNER + kbase + k0 + ke);
    }
    // stage B tile [48][64] via registers
    for (int i = tid; i < 384; i += 256) {
      int brow = i >> 3, kc = (i & 7) * 8;
      *(bf16x8*)&sB[brow * 64 + kc] = *(const bf16x8*)(Bw + (size_t)brow * DINNER + kbase + k0 + kc);
    }
    __syncthreads();
    bf16x8 af[2][2], bf_[3][2];
#pragma unroll
    for (int m = 0; m < 2; ++m)
#pragma unroll
      for (int ks = 0; ks < 2; ++ks)
        af[m][ks] = *(const bf16x8*)&sA[(wid * 32 + m * 16 + frow) * 64 + ks * 32 + fke];
#pragma unroll
    for (int n = 0; n < 3; ++n)
#pragma unroll
      for (int ks = 0; ks < 2; ++ks)
        bf_[n][ks] = *(const bf16x8*)&sB[(n * 16 + frow) * 64 + ks * 32 + fke];
#pragma unroll
    for (int m = 0; m < 2; ++m)
#pragma unroll
      for (int n = 0; n < 3; ++n)
#pragma unroll
        for (int ks = 0; ks < 2; ++ks)
          acc[m][n] = __builtin_amdgcn_mfma_f32_16x16x32_bf16(af[m][ks], bf_[n][ks], acc[m][n], 0, 0, 0);
    __syncthreads();
  }
  float* po = part + (size_t)blockIdx.y * (T_SEQ * 48);
#pragma unroll
  for (int m = 0; m < 2; ++m)
#pragma unroll
    for (int n = 0; n < 3; ++n)
#pragma unroll
      for (int j = 0; j < 4; ++j) {
        int rr = mbase + wid * 32 + m * 16 + (lane >> 4) * 4 + j;
        int cc = n * 16 + (lane & 15);
        po[(size_t)rr * 48 + cc] = acc[m][n][j];
      }
}

__global__ __launch_bounds__(256) void reduce4(const float* __restrict__ part,
                                               float* __restrict__ xdbl) {
  int i = blockIdx.x * 256 + threadIdx.x;   // over 8192*48/4 = 98304
  const float4* p = (const float4*)part;
  float4 a = p[i], b = p[i + 98304], c = p[i + 2 * 98304], d = p[i + 3 * 98304];
  ((float4*)xdbl)[i] = make_float4(a.x + b.x + c.x + d.x, a.y + b.y + c.y + d.y,
                                   a.z + b.z + c.z + d.z, a.w + b.w + c.w + d.w);
}

// ---------------- depthwise causal conv (DC=4) + silu ----------------
__global__ __launch_bounds__(256) void conv_silu(const ushort* __restrict__ xz,
                                                 const float* __restrict__ cw,
                                                 const float* __restrict__ cb,
                                                 ushort* __restrict__ xs) {
  int idx = blockIdx.x * 256 + threadIdx.x;   // t*2048 + d
  int t = idx >> 11, d = idx & 2047;
  float4 w = *(const float4*)(cw + d * 4);
  float a = cb[d];
  const float wk[4] = {w.x, w.y, w.z, w.w};
#pragma unroll
  for (int k = 0; k < 4; ++k) {
    int tt = t - 3 + k;
    if (tt >= 0) a += bf2f(xz[(size_t)tt * 4096 + d]) * wk[k];
  }
  float s = a / (1.f + expf(-a));
  xs[idx] = f2bf(s);
}

// ---------------- scan precompute (xdbl stride 48 now) ----------------
__global__ __launch_bounds__(256) void precompute_k(const float* __restrict__ xdbl,
                                                    const float* __restrict__ A_log,
                                                    float* __restrict__ abar,
                                                    float* __restrict__ bbar,
                                                    float* __restrict__ cc,
                                                    float* __restrict__ dlt) {
  int t = blockIdx.x * 256 + threadIdx.x;
  if (t >= T_SEQ) return;
  const float* r = xdbl + (size_t)t * 48;
  float v = r[0];
  float delta = (v > 20.f) ? v : log1pf(expf(v));
  dlt[t] = delta;
#pragma unroll
  for (int n = 0; n < NSTATE; ++n) {
    float A = -expf(A_log[n]);
    abar[t * 16 + n] = expf(delta * A);
    bbar[t * 16 + n] = delta * r[1 + n];
    cc[t * 16 + n]   = r[17 + n];
  }
}

__global__ __launch_bounds__(256) void chunkprod_k(const float* __restrict__ dlt,
                                                   const float* __restrict__ A_log,
                                                   float* __restrict__ P) {
  int idx = blockIdx.x * 256 + threadIdx.x;
  if (idx >= NCH * NSTATE) return;
  int c = idx >> 4, n = idx & 15;
  float s = 0.f;
  for (int i = 0; i < CL; ++i) s += dlt[c * CL + i];
  P[idx] = expf(-expf(A_log[n]) * s);
}

// ---------------- scan pass 1 ----------------
__global__ __launch_bounds__(256) void scan1(const ushort* __restrict__ xs,
                                             const float* __restrict__ abar,
                                             const float* __restrict__ bbar,
                                             float* __restrict__ hend) {
  int c = blockIdx.x;
  int d = blockIdx.y * 256 + threadIdx.x;
  __shared__ float s_ab[CL * 16], s_bb[CL * 16];
  for (int e = threadIdx.x; e < CL * 16; e += 256) {
    s_ab[e] = abar[(size_t)c * CL * 16 + e];
    s_bb[e] = bbar[(size_t)c * CL * 16 + e];
  }
  __syncthreads();
  float h[16];
#pragma unroll
  for (int n = 0; n < 16; ++n) h[n] = 0.f;
  int tbase = c * CL;
  for (int i = 0; i < CL; ++i) {
    float x = bf2f(xs[(size_t)(tbase + i) * DINNER + d]);
#pragma unroll
    for (int n = 0; n < 16; ++n) h[n] = s_ab[i * 16 + n] * h[n] + s_bb[i * 16 + n] * x;
  }
  float* o = hend + ((size_t)c * DINNER + d) * 16;
#pragma unroll
  for (int qq = 0; qq < 4; ++qq)
    ((float4*)o)[qq] = make_float4(h[4 * qq], h[4 * qq + 1], h[4 * qq + 2], h[4 * qq + 3]);
}

// ---------------- scan pass 2 ----------------
__global__ __launch_bounds__(256) void scan2(const float* __restrict__ hend,
                                             const float* __restrict__ P,
                                             float* __restrict__ hin) {
  int idx = blockIdx.x * 256 + threadIdx.x;
  int n = idx & 15;
  float h = 0.f;
  for (int c = 0; c < NCH; ++c) {
    hin[(size_t)c * (DINNER * 16) + idx] = h;
    h = P[c * 16 + n] * h + hend[(size_t)c * (DINNER * 16) + idx];
  }
}

// ---------------- scan pass 3 ----------------
__global__ __launch_bounds__(256) void scan3(const ushort* __restrict__ xs,
                                             const ushort* __restrict__ xz,
                                             const float* __restrict__ abar,
                                             const float* __restrict__ bbar,
                                             const float* __restrict__ cc,
                                             const float* __restrict__ hin,
                                             const float* __restrict__ Dv,
                                             ushort* __restrict__ y) {
  int c = blockIdx.x;
  int d = blockIdx.y * 256 + threadIdx.x;
  __shared__ float s_ab[CL * 16], s_bb[CL * 16], s_cc[CL * 16];
  for (int e = threadIdx.x; e < CL * 16; e += 256) {
    s_ab[e] = abar[(size_t)c * CL * 16 + e];
    s_bb[e] = bbar[(size_t)c * CL * 16 + e];
    s_cc[e] = cc[(size_t)c * CL * 16 + e];
  }
  __syncthreads();
  float h[16];
  const float* hi = hin + ((size_t)c * DINNER + d) * 16;
#pragma unroll
  for (int qq = 0; qq < 4; ++qq) {
    float4 v = ((const float4*)hi)[qq];
    h[4 * qq] = v.x; h[4 * qq + 1] = v.y; h[4 * qq + 2] = v.z; h[4 * qq + 3] = v.w;
  }
  float Dd = Dv[d];
  int tbase = c * CL;
  for (int i = 0; i < CL; ++i) {
    size_t t = tbase + i;
    float x = bf2f(xs[t * DINNER + d]);
    float ys = 0.f;
#pragma unroll
    for (int n = 0; n < 16; ++n) {
      h[n] = s_ab[i * 16 + n] * h[n] + s_bb[i * 16 + n] * x;
      ys += s_cc[i * 16 + n] * h[n];
    }
    float z = bf2f(xz[t * 4096 + 2048 + d]);
    float yv = (ys + Dd * x) * (z / (1.f + expf(-z)));
    y[t * DINNER + d] = f2bf(yv);
  }
}

// ---------------- launch ----------------
extern "C" void kernel_launch(void* const* d_in, const int* in_sizes, int n_in,
                              void* d_out, int out_size, void* d_ws, size_t ws_size,
                              hipStream_t stream) {
  const float* x      = (const float*)d_in[0];
  const float* W_in   = (const float*)d_in[1];
  const float* conv_w = (const float*)d_in[2];
  const float* conv_b = (const float*)d_in[3];
  const float* W_x    = (const float*)d_in[4];
  const float* A_log  = (const float*)d_in[5];
  const float* Dv     = (const float*)d_in[6];
  const float* W_out  = (const float*)d_in[7];
  float* out = (float*)d_out;

  char* w = (char*)d_ws;
  auto alloc = [&](size_t bytes) { char* p = w; w += (bytes + 255) & ~(size_t)255; return p; };

  ushort* xbf   = (ushort*)alloc((size_t)T_SEQ * DMODEL * 2);
  ushort* winT  = (ushort*)alloc((size_t)4096 * 1024 * 2);
  ushort* woutT = (ushort*)alloc((size_t)1024 * 2048 * 2);
  ushort* wxT   = (ushort*)alloc((size_t)48 * 2048 * 2);
  ushort* xz    = (ushort*)alloc((size_t)T_SEQ * 4096 * 2);
  ushort* xs    = (ushort*)alloc((size_t)T_SEQ * DINNER * 2);
  float*  xdbl  = (float*) alloc((size_t)T_SEQ * 48 * 4);
  float*  parts = (float*) alloc((size_t)4 * T_SEQ * 48 * 4);
  float*  abar  = (float*) alloc((size_t)T_SEQ * 16 * 4);
  float*  bbar  = (float*) alloc((size_t)T_SEQ * 16 * 4);
  float*  ccb   = (float*) alloc((size_t)T_SEQ * 16 * 4);
  float*  dlt   = (float*) alloc((size_t)T_SEQ * 4);
  float*  P     = (float*) alloc((size_t)NCH * 16 * 4);
  float*  hend  = (float*) alloc((size_t)NCH * DINNER * 16 * 4);
  float*  hin   = (float*) alloc((size_t)NCH * DINNER * 16 * 4);
  ushort* ybf   = (ushort*)alloc((size_t)T_SEQ * DINNER * 2);

  auto kg1 = gemm256<1>;
  auto kg0 = gemm256<0>;
  hipFuncSetAttribute(reinterpret_cast<const void*>(kg1),
                      hipFuncAttributeMaxDynamicSharedMemorySize, 131072);
  hipFuncSetAttribute(reinterpret_cast<const void*>(kg0),
                      hipFuncAttributeMaxDynamicSharedMemorySize, 131072);

  // prep
  cast_bf16<<<(T_SEQ * DMODEL / 4 + 255) / 256, 256, 0, stream>>>(x, xbf, T_SEQ * DMODEL / 4);
  transpose_bf16<<<dim3(4096 / 32, 1024 / 32), dim3(32, 8), 0, stream>>>(W_in, winT, 1024, 4096);
  transpose_bf16<<<dim3(1024 / 32, 2048 / 32), dim3(32, 8), 0, stream>>>(W_out, woutT, 2048, 1024);
  wx_transpose_pad<<<(48 * 2048) / 256, 256, 0, stream>>>(W_x, wxT);

  // GEMM1: xz = x @ W_in   (8192 x 4096, K=1024), bf16 out
  kg1<<<dim3((T_SEQ / 256) * (4096 / 256)), 512, 131072, stream>>>(xbf, winT, xz, 4096, 1024, 4096 / 256);

  // conv + silu
  conv_silu<<<(T_SEQ * DINNER) / 256, 256, 0, stream>>>(xz, conv_w, conv_b, xs);

  // GEMM2: xdbl = xs @ W_x (N=48 pad, split-K 4)
  gemm_thin<<<dim3(T_SEQ / 128, 4), 256, 0, stream>>>(xs, wxT, parts);
  reduce4<<<(T_SEQ * 48 / 4) / 256, 256, 0, stream>>>(parts, xdbl);

  // scan precompute
  precompute_k<<<T_SEQ / 256, 256, 0, stream>>>(xdbl, A_log, abar, bbar, ccb, dlt);
  chunkprod_k<<<(NCH * 16 + 255) / 256, 256, 0, stream>>>(dlt, A_log, P);

  // 3-pass chunked scan
  scan1<<<dim3(NCH, DINNER / 256), 256, 0, stream>>>(xs, abar, bbar, hend);
  scan2<<<(DINNER * 16) / 256, 256, 0, stream>>>(hend, P, hin);
  scan3<<<dim3(NCH, DINNER / 256), 256, 0, stream>>>(xs, xz, abar, bbar, ccb, hin, Dv, ybf);

  // GEMM3: out = y @ W_out (8192 x 1024, K=2048), f32 out
  kg0<<<dim3((T_SEQ / 256) * (1024 / 256)), 512, 131072, stream>>>(ybf, woutT, out, 1024, 2048, 1024 / 256);
}

// Round 3
// 310.361 us; speedup vs baseline: 1.3110x; 1.3110x over previous
//
#include <hip/hip_runtime.h>
#include <hip/hip_bf16.h>

// ---------------- problem constants ----------------
#define T_SEQ 8192
#define DMODEL 1024
#define DINNER 2048          // DI
#define NSTATE 16            // DS
#define NCH 128              // scan chunks
#define CL 64                // chunk length (NCH*CL = T_SEQ)

typedef __attribute__((ext_vector_type(8))) short bf16x8;   // 8 bf16 = 4 VGPRs (MFMA A/B frag)
typedef __attribute__((ext_vector_type(4))) float f32x4;    // MFMA C/D frag

__device__ __forceinline__ float bf2f(ushort u) {
  union { unsigned u; float f; } c; c.u = ((unsigned)u) << 16; return c.f;
}
__device__ __forceinline__ ushort f2bf(float f) {
  union { float f; unsigned u; } c; c.f = f;
  unsigned r = c.u + 0x7FFFu + ((c.u >> 16) & 1u);   // RNE
  return (ushort)(r >> 16);
}

#define GLD16(dst, src) __builtin_amdgcn_global_load_lds( \
    (const __attribute__((address_space(1))) void*)(src), \
    (__attribute__((address_space(3))) void*)(dst), 16, 0, 0)

template<int N> __device__ __forceinline__ void waitcnt_vm() {
  asm volatile("s_waitcnt vmcnt(%0)" :: "i"(N) : "memory");
}

// ---------------- prep kernels ----------------
__global__ __launch_bounds__(256) void cast_bf16(const float* __restrict__ in,
                                                 ushort* __restrict__ out, int n4) {
  int i = blockIdx.x * 256 + threadIdx.x;
  if (i < n4) {
    float4 v = ((const float4*)in)[i];
    ushort4 o;
    o.x = f2bf(v.x); o.y = f2bf(v.y); o.z = f2bf(v.z); o.w = f2bf(v.w);
    ((ushort4*)out)[i] = o;
  }
}

// in[R][C] f32 -> out[C][R] bf16   (grid: (C/32, R/32), block (32,8))
__global__ __launch_bounds__(256) void transpose_bf16(const float* __restrict__ in,
                                                      ushort* __restrict__ out, int R, int C) {
  __shared__ float tile[32][33];
  int bx = blockIdx.x * 32;   // C base
  int by = blockIdx.y * 32;   // R base
  int x = threadIdx.x, y = threadIdx.y;
#pragma unroll
  for (int j = 0; j < 32; j += 8)
    tile[y + j][x] = in[(size_t)(by + y + j) * C + bx + x];
  __syncthreads();
#pragma unroll
  for (int j = 0; j < 32; j += 8)
    out[(size_t)(bx + y + j) * R + by + x] = f2bf(tile[x][y + j]);
}

// W_x[2048][33] f32 -> wx48[48][2048] bf16 (transposed, zero-padded rows 33..47)
__global__ __launch_bounds__(256) void wx_transpose_pad(const float* __restrict__ Wx,
                                                        ushort* __restrict__ wxT) {
  int idx = blockIdx.x * 256 + threadIdx.x;   // 48*2048
  int j = idx >> 11;
  int k = idx & 2047;
  wxT[idx] = (j < 33) ? f2bf(Wx[k * 33 + j]) : (ushort)0;
}

// ---------------- 4-deep pipelined GEMM, BK=32 ----------------
// C[M][N] = A[M][K] * B^T, A/B bf16 row-major K-contig.
// Wave grid MW x NW (8 waves, 512 thr); per-wave output (MR*16) x (NR*16).
// LDS: 4 buffers x (A BM*64B + B BN*64B). Staging: tile t+3 issued during
// tile t (A in phase a, B in phase b) -> ~2.5 tiles issue->use slack.
// Buffer safety: (t+3) mod 4 == (t-1) mod 4, whose reads ended a tile ago.
// Counted vmcnt(2L) per tile forces t+1 landed, leaves t+2/t+3 in flight.
// Swizzle: 16B granule g stored at g^(row&3) -> conflict-free ds_read_b128
// (2 lanes/bank = wave64 minimum). Applied via pre-swizzled global source
// (linear global_load_lds dest, rule #21), same XOR on read side.
template<int BF16OUT, int MW, int NW, int MR, int NR>
__global__ __launch_bounds__(512, 2)
void gemm_pipe(const ushort* __restrict__ A, const ushort* __restrict__ B,
               void* __restrict__ Cout, int N, int K, int nbn) {
  constexpr int BM = MW * MR * 16;
  constexpr int BN = NW * NR * 16;
  constexpr int RA = BM / 128;          // A stage rounds (GLD16 per thread)
  constexpr int RB = BN / 128;
  constexpr int L  = RA + RB;           // loads/thread/tile
  extern __shared__ __align__(16) char smem[];
  char* const sB = smem + 4 * BM * 64;

  const int tid = threadIdx.x, lane = tid & 63, wid = tid >> 6;
  const int wm = wid / NW, wn = wid % NW;

  // XCD-bijective swizzle (m204)
  const int nwg = gridDim.x;
  const int q = nwg >> 3, r = nwg & 7;
  const int xcd = blockIdx.x & 7, bidx = blockIdx.x >> 3;
  const int wg = (xcd < r ? xcd * (q + 1) : r * (q + 1) + (xcd - r) * q) + bidx;
  const int mbase = (wg / nbn) * BM;
  const int nbase = (wg % nbn) * BN;
  const int NT = K >> 5;

  // staging source (pre-swizzled): LDS granule (tid&3) <- global granule ^(row&3)
  const int srow = tid >> 2;
  const int scol = ((tid & 3) ^ (srow & 3)) << 3;   // element offset
  const ushort* pa[RA];
  const ushort* pb[RB];
#pragma unroll
  for (int j = 0; j < RA; ++j) pa[j] = A + (size_t)(mbase + j * 128 + srow) * K + scol;
#pragma unroll
  for (int j = 0; j < RB; ++j) pb[j] = B + (size_t)(nbase + j * 128 + srow) * K + scol;

  auto stageA = [&](int tt) {
    char* d = smem + (tt & 3) * (BM * 64) + wid * 1024;
#pragma unroll
    for (int j = 0; j < RA; ++j) GLD16(d + j * 8192, pa[j] + tt * 32);
  };
  auto stageB = [&](int tt) {
    char* d = sB + (tt & 3) * (BN * 64) + wid * 1024;
#pragma unroll
    for (int j = 0; j < RB; ++j) GLD16(d + j * 8192, pb[j] + tt * 32);
  };

  // ds_read offsets (swizzled)
  const int frow = lane & 15;
  const int gsw = (((lane >> 4) ^ (frow & 3)) << 4);
  const int aoff0 = (wm * MR * 16 + frow) * 64 + gsw;
  const int boff0 = (wn * NR * 16 + frow) * 64 + gsw;

  f32x4 acc[MR][NR];
#pragma unroll
  for (int m = 0; m < MR; ++m)
#pragma unroll
    for (int n = 0; n < NR; ++n) acc[m][n] = (f32x4){0.f, 0.f, 0.f, 0.f};

  // prologue: tiles 0,1,2 in flight; force tile 0 landed
#pragma unroll
  for (int tt = 0; tt < 3; ++tt) if (tt < NT) { stageA(tt); stageB(tt); }
  waitcnt_vm<2 * L>();
  __builtin_amdgcn_s_barrier();

  for (int t = 0; t < NT; ++t) {
    const char* bufA = smem + (t & 3) * (BM * 64);
    const char* bufB = sB + (t & 3) * (BN * 64);
    bf16x8 af[MR], bfr[NR];
#pragma unroll
    for (int m = 0; m < MR; ++m) af[m] = *(const bf16x8*)(bufA + aoff0 + m * 1024);
#pragma unroll
    for (int n = 0; n < NR; ++n) bfr[n] = *(const bf16x8*)(bufB + boff0 + n * 1024);
    if (t + 3 < NT) stageA(t + 3);
    __builtin_amdgcn_s_barrier();
    asm volatile("s_waitcnt lgkmcnt(0)" ::: "memory");
    __builtin_amdgcn_s_setprio(1);
#pragma unroll
    for (int m = 0; m < MR / 2; ++m)
#pragma unroll
      for (int n = 0; n < NR; ++n)
        acc[m][n] = __builtin_amdgcn_mfma_f32_16x16x32_bf16(af[m], bfr[n], acc[m][n], 0, 0, 0);
    __builtin_amdgcn_s_setprio(0);
    __builtin_amdgcn_s_barrier();
    if (t + 3 < NT) stageB(t + 3);
    __builtin_amdgcn_s_setprio(1);
#pragma unroll
    for (int m = MR / 2; m < MR; ++m)
#pragma unroll
      for (int n = 0; n < NR; ++n)
        acc[m][n] = __builtin_amdgcn_mfma_f32_16x16x32_bf16(af[m], bfr[n], acc[m][n], 0, 0, 0);
    __builtin_amdgcn_s_setprio(0);
    // counted vmcnt: leave L*min(NT-2-t, 2) in flight (force t+1 landed)
    if (t + 4 <= NT)      waitcnt_vm<2 * L>();
    else if (t + 3 <= NT) waitcnt_vm<L>();
    else if (t + 2 <= NT) waitcnt_vm<0>();
    __builtin_amdgcn_s_barrier();
  }

  // epilogue: C/D layout col=lane&15, row=(lane>>4)*4+reg  [m89/m91]
  const int crow0 = mbase + wm * MR * 16 + (lane >> 4) * 4;
  const int ccol0 = nbase + wn * NR * 16 + (lane & 15);
#pragma unroll
  for (int m = 0; m < MR; ++m)
#pragma unroll
    for (int n = 0; n < NR; ++n)
#pragma unroll
      for (int j = 0; j < 4; ++j) {
        int rr = crow0 + m * 16 + j;
        int cc = ccol0 + n * 16;
        float v = acc[m][n][j];
        if (BF16OUT) ((ushort*)Cout)[(size_t)rr * N + cc] = f2bf(v);
        else         ((float*) Cout)[(size_t)rr * N + cc] = v;
      }
}

// ---------------- thin GEMM: xdbl = xs @ W_x (N=48 pad), 4-way split-K ----------------
__global__ __launch_bounds__(256) void gemm_thin(const ushort* __restrict__ A,
                                                 const ushort* __restrict__ Bw,
                                                 float* __restrict__ part) {
  __shared__ __align__(16) ushort sA[128 * 64];   // 16 KB
  __shared__ __align__(16) ushort sB[48 * 64];    // 6 KB
  const int tid = threadIdx.x, lane = tid & 63, wid = tid >> 6;
  const int mbase = blockIdx.x * 128;
  const int kbase = blockIdx.y * 512;
  const int frow = lane & 15, fke = (lane >> 4) * 8;

  f32x4 acc[2][3];
#pragma unroll
  for (int m = 0; m < 2; ++m)
#pragma unroll
    for (int n = 0; n < 3; ++n) acc[m][n] = (f32x4){0.f, 0.f, 0.f, 0.f};

  for (int k0 = 0; k0 < 512; k0 += 64) {
#pragma unroll
    for (int j = 0; j < 4; ++j) {
      int o = tid * 16 + j * 4096;
      int row = o >> 7, ke = ((o >> 4) & 7) * 8;
      GLD16((char*)sA + wid * 1024 + j * 4096,
            A + (size_t)(mbase + row) * DINNER + kbase + k0 + ke);
    }
    for (int i = tid; i < 384; i += 256) {
      int brow = i >> 3, kc = (i & 7) * 8;
      *(bf16x8*)&sB[brow * 64 + kc] = *(const bf16x8*)(Bw + (size_t)brow * DINNER + kbase + k0 + kc);
    }
    __syncthreads();
    bf16x8 af[2][2], bf_[3][2];
#pragma unroll
    for (int m = 0; m < 2; ++m)
#pragma unroll
      for (int ks = 0; ks < 2; ++ks)
        af[m][ks] = *(const bf16x8*)&sA[(wid * 32 + m * 16 + frow) * 64 + ks * 32 + fke];
#pragma unroll
    for (int n = 0; n < 3; ++n)
#pragma unroll
      for (int ks = 0; ks < 2; ++ks)
        bf_[n][ks] = *(const bf16x8*)&sB[(n * 16 + frow) * 64 + ks * 32 + fke];
#pragma unroll
    for (int m = 0; m < 2; ++m)
#pragma unroll
      for (int n = 0; n < 3; ++n)
#pragma unroll
        for (int ks = 0; ks < 2; ++ks)
          acc[m][n] = __builtin_amdgcn_mfma_f32_16x16x32_bf16(af[m][ks], bf_[n][ks], acc[m][n], 0, 0, 0);
    __syncthreads();
  }
  float* po = part + (size_t)blockIdx.y * (T_SEQ * 48);
#pragma unroll
  for (int m = 0; m < 2; ++m)
#pragma unroll
    for (int n = 0; n < 3; ++n)
#pragma unroll
      for (int j = 0; j < 4; ++j) {
        int rr = mbase + wid * 32 + m * 16 + (lane >> 4) * 4 + j;
        int cc = n * 16 + (lane & 15);
        po[(size_t)rr * 48 + cc] = acc[m][n][j];
      }
}

__global__ __launch_bounds__(256) void reduce4(const float* __restrict__ part,
                                               float* __restrict__ xdbl) {
  int i = blockIdx.x * 256 + threadIdx.x;
  const float4* p = (const float4*)part;
  float4 a = p[i], b = p[i + 98304], c = p[i + 2 * 98304], d = p[i + 3 * 98304];
  ((float4*)xdbl)[i] = make_float4(a.x + b.x + c.x + d.x, a.y + b.y + c.y + d.y,
                                   a.z + b.z + c.z + d.z, a.w + b.w + c.w + d.w);
}

// ---------------- depthwise causal conv (DC=4) + silu ----------------
__global__ __launch_bounds__(256) void conv_silu(const ushort* __restrict__ xz,
                                                 const float* __restrict__ cw,
                                                 const float* __restrict__ cb,
                                                 ushort* __restrict__ xs) {
  int idx = blockIdx.x * 256 + threadIdx.x;   // t*2048 + d
  int t = idx >> 11, d = idx & 2047;
  float4 w = *(const float4*)(cw + d * 4);
  float a = cb[d];
  const float wk[4] = {w.x, w.y, w.z, w.w};
#pragma unroll
  for (int k = 0; k < 4; ++k) {
    int tt = t - 3 + k;
    if (tt >= 0) a += bf2f(xz[(size_t)tt * 4096 + d]) * wk[k];
  }
  float s = a / (1.f + expf(-a));
  xs[idx] = f2bf(s);
}

// ---------------- scan precompute (xdbl stride 48) ----------------
__global__ __launch_bounds__(256) void precompute_k(const float* __restrict__ xdbl,
                                                    const float* __restrict__ A_log,
                                                    float* __restrict__ abar,
                                                    float* __restrict__ bbar,
                                                    float* __restrict__ cc,
                                                    float* __restrict__ dlt) {
  int t = blockIdx.x * 256 + threadIdx.x;
  if (t >= T_SEQ) return;
  const float* r = xdbl + (size_t)t * 48;
  float v = r[0];
  float delta = (v > 20.f) ? v : log1pf(expf(v));
  dlt[t] = delta;
#pragma unroll
  for (int n = 0; n < NSTATE; ++n) {
    float A = -expf(A_log[n]);
    abar[t * 16 + n] = expf(delta * A);
    bbar[t * 16 + n] = delta * r[1 + n];
    cc[t * 16 + n]   = r[17 + n];
  }
}

__global__ __launch_bounds__(256) void chunkprod_k(const float* __restrict__ dlt,
                                                   const float* __restrict__ A_log,
                                                   float* __restrict__ P) {
  int idx = blockIdx.x * 256 + threadIdx.x;
  if (idx >= NCH * NSTATE) return;
  int c = idx >> 4, n = idx & 15;
  float s = 0.f;
  for (int i = 0; i < CL; ++i) s += dlt[c * CL + i];
  P[idx] = expf(-expf(A_log[n]) * s);
}

// ---------------- scan pass 1 ----------------
__global__ __launch_bounds__(256) void scan1(const ushort* __restrict__ xs,
                                             const float* __restrict__ abar,
                                             const float* __restrict__ bbar,
                                             float* __restrict__ hend) {
  int c = blockIdx.x;
  int d = blockIdx.y * 256 + threadIdx.x;
  __shared__ float s_ab[CL * 16], s_bb[CL * 16];
  for (int e = threadIdx.x; e < CL * 16; e += 256) {
    s_ab[e] = abar[(size_t)c * CL * 16 + e];
    s_bb[e] = bbar[(size_t)c * CL * 16 + e];
  }
  __syncthreads();
  float h[16];
#pragma unroll
  for (int n = 0; n < 16; ++n) h[n] = 0.f;
  int tbase = c * CL;
  for (int i = 0; i < CL; ++i) {
    float x = bf2f(xs[(size_t)(tbase + i) * DINNER + d]);
#pragma unroll
    for (int n = 0; n < 16; ++n) h[n] = s_ab[i * 16 + n] * h[n] + s_bb[i * 16 + n] * x;
  }
  float* o = hend + ((size_t)c * DINNER + d) * 16;
#pragma unroll
  for (int qq = 0; qq < 4; ++qq)
    ((float4*)o)[qq] = make_float4(h[4 * qq], h[4 * qq + 1], h[4 * qq + 2], h[4 * qq + 3]);
}

// ---------------- scan pass 2 ----------------
__global__ __launch_bounds__(256) void scan2(const float* __restrict__ hend,
                                             const float* __restrict__ P,
                                             float* __restrict__ hin) {
  int idx = blockIdx.x * 256 + threadIdx.x;
  int n = idx & 15;
  float h = 0.f;
  for (int c = 0; c < NCH; ++c) {
    hin[(size_t)c * (DINNER * 16) + idx] = h;
    h = P[c * 16 + n] * h + hend[(size_t)c * (DINNER * 16) + idx];
  }
}

// ---------------- scan pass 3 ----------------
__global__ __launch_bounds__(256) void scan3(const ushort* __restrict__ xs,
                                             const ushort* __restrict__ xz,
                                             const float* __restrict__ abar,
                                             const float* __restrict__ bbar,
                                             const float* __restrict__ cc,
                                             const float* __restrict__ hin,
                                             const float* __restrict__ Dv,
                                             ushort* __restrict__ y) {
  int c = blockIdx.x;
  int d = blockIdx.y * 256 + threadIdx.x;
  __shared__ float s_ab[CL * 16], s_bb[CL * 16], s_cc[CL * 16];
  for (int e = threadIdx.x; e < CL * 16; e += 256) {
    s_ab[e] = abar[(size_t)c * CL * 16 + e];
    s_bb[e] = bbar[(size_t)c * CL * 16 + e];
    s_cc[e] = cc[(size_t)c * CL * 16 + e];
  }
  __syncthreads();
  float h[16];
  const float* hi = hin + ((size_t)c * DINNER + d) * 16;
#pragma unroll
  for (int qq = 0; qq < 4; ++qq) {
    float4 v = ((const float4*)hi)[qq];
    h[4 * qq] = v.x; h[4 * qq + 1] = v.y; h[4 * qq + 2] = v.z; h[4 * qq + 3] = v.w;
  }
  float Dd = Dv[d];
  int tbase = c * CL;
  for (int i = 0; i < CL; ++i) {
    size_t t = tbase + i;
    float x = bf2f(xs[t * DINNER + d]);
    float ys = 0.f;
#pragma unroll
    for (int n = 0; n < 16; ++n) {
      h[n] = s_ab[i * 16 + n] * h[n] + s_bb[i * 16 + n] * x;
      ys += s_cc[i * 16 + n] * h[n];
    }
    float z = bf2f(xz[t * 4096 + 2048 + d]);
    float yv = (ys + Dd * x) * (z / (1.f + expf(-z)));
    y[t * DINNER + d] = f2bf(yv);
  }
}

// ---------------- launch ----------------
extern "C" void kernel_launch(void* const* d_in, const int* in_sizes, int n_in,
                              void* d_out, int out_size, void* d_ws, size_t ws_size,
                              hipStream_t stream) {
  const float* x      = (const float*)d_in[0];
  const float* W_in   = (const float*)d_in[1];
  const float* conv_w = (const float*)d_in[2];
  const float* conv_b = (const float*)d_in[3];
  const float* W_x    = (const float*)d_in[4];
  const float* A_log  = (const float*)d_in[5];
  const float* Dv     = (const float*)d_in[6];
  const float* W_out  = (const float*)d_in[7];
  float* out = (float*)d_out;

  char* w = (char*)d_ws;
  auto alloc = [&](size_t bytes) { char* p = w; w += (bytes + 255) & ~(size_t)255; return p; };

  ushort* xbf   = (ushort*)alloc((size_t)T_SEQ * DMODEL * 2);
  ushort* winT  = (ushort*)alloc((size_t)4096 * 1024 * 2);
  ushort* woutT = (ushort*)alloc((size_t)1024 * 2048 * 2);
  ushort* wxT   = (ushort*)alloc((size_t)48 * 2048 * 2);
  ushort* xz    = (ushort*)alloc((size_t)T_SEQ * 4096 * 2);
  ushort* xs    = (ushort*)alloc((size_t)T_SEQ * DINNER * 2);
  float*  xdbl  = (float*) alloc((size_t)T_SEQ * 48 * 4);
  float*  parts = (float*) alloc((size_t)4 * T_SEQ * 48 * 4);
  float*  abar  = (float*) alloc((size_t)T_SEQ * 16 * 4);
  float*  bbar  = (float*) alloc((size_t)T_SEQ * 16 * 4);
  float*  ccb   = (float*) alloc((size_t)T_SEQ * 16 * 4);
  float*  dlt   = (float*) alloc((size_t)T_SEQ * 4);
  float*  P     = (float*) alloc((size_t)NCH * 16 * 4);
  float*  hend  = (float*) alloc((size_t)NCH * DINNER * 16 * 4);
  float*  hin   = (float*) alloc((size_t)NCH * DINNER * 16 * 4);
  ushort* ybf   = (ushort*)alloc((size_t)T_SEQ * DINNER * 2);

  // GEMM1: 256x256 tile (2x4 waves, 8x4 frags). GEMM3: 256x128 (4x2 waves, 4x4).
  auto kg1 = gemm_pipe<1, 2, 4, 8, 4>;
  auto kg3 = gemm_pipe<0, 4, 2, 4, 4>;
  hipFuncSetAttribute(reinterpret_cast<const void*>(kg1),
                      hipFuncAttributeMaxDynamicSharedMemorySize, 131072);
  hipFuncSetAttribute(reinterpret_cast<const void*>(kg3),
                      hipFuncAttributeMaxDynamicSharedMemorySize, 98304);

  // prep
  cast_bf16<<<(T_SEQ * DMODEL / 4 + 255) / 256, 256, 0, stream>>>(x, xbf, T_SEQ * DMODEL / 4);
  transpose_bf16<<<dim3(4096 / 32, 1024 / 32), dim3(32, 8), 0, stream>>>(W_in, winT, 1024, 4096);
  transpose_bf16<<<dim3(1024 / 32, 2048 / 32), dim3(32, 8), 0, stream>>>(W_out, woutT, 2048, 1024);
  wx_transpose_pad<<<(48 * 2048) / 256, 256, 0, stream>>>(W_x, wxT);

  // GEMM1: xz = x @ W_in (8192x4096, K=1024), bf16 out; 512 blocks
  kg1<<<dim3((T_SEQ / 256) * (4096 / 256)), 512, 131072, stream>>>(xbf, winT, xz, 4096, 1024, 4096 / 256);

  // conv + silu
  conv_silu<<<(T_SEQ * DINNER) / 256, 256, 0, stream>>>(xz, conv_w, conv_b, xs);

  // GEMM2: xdbl = xs @ W_x (N=48 pad, split-K 4)
  gemm_thin<<<dim3(T_SEQ / 128, 4), 256, 0, stream>>>(xs, wxT, parts);
  reduce4<<<(T_SEQ * 48 / 4) / 256, 256, 0, stream>>>(parts, xdbl);

  // scan precompute
  precompute_k<<<T_SEQ / 256, 256, 0, stream>>>(xdbl, A_log, abar, bbar, ccb, dlt);
  chunkprod_k<<<(NCH * 16 + 255) / 256, 256, 0, stream>>>(dlt, A_log, P);

  // 3-pass chunked scan
  scan1<<<dim3(NCH, DINNER / 256), 256, 0, stream>>>(xs, abar, bbar, hend);
  scan2<<<(DINNER * 16) / 256, 256, 0, stream>>>(hend, P, hin);
  scan3<<<dim3(NCH, DINNER / 256), 256, 0, stream>>>(xs, xz, abar, bbar, ccb, hin, Dv, ybf);

  // GEMM3: out = y @ W_out (8192x1024, K=2048), f32 out; 256 blocks
  kg3<<<dim3((T_SEQ / 256) * (1024 / 128)), 512, 98304, stream>>>(ybf, woutT, out, 1024, 2048, 1024 / 128);
}